// Round 15
// baseline (97.165 us; speedup 1.0000x reference)
//
#include <hip/hip_runtime.h>

#define NSTATE 128
#define NM1    127
#define UDIM   4

typedef float v4f  __attribute__((ext_vector_type(4)));
typedef _Float16 h2 __attribute__((ext_vector_type(2)));

// R15: identical to R14 except ONE change: plain stores instead of
// nontemporal. Rationale: fillBuffer (7 TB/s reference) uses plain stores --
// full-line writes land in L2 without RFO and write-back coalesces
// consecutive wave-stores into long sequential HBM bursts; nt bypasses L2
// and emits 512B granules straight to the MC. The W table is LDS-resident
// now, so L2 pollution by the output stream no longer hurts reads.
// Structure (from R14): 128KB fp16 de-interleaved W table in LDS; 256 blocks
// x 1024 thr (16 waves, 1 block/CU); each block sweeps a CONTIGUOUS span of
// row-pairs (lanes 0-31 = row 2p, 32-63 = row 2p+1, lane owns 4 cols);
// conflict-free ds_read_b128 x2; v_dot2_f32_f16 dots; no-max softmax
// (validated R2-R14, absmax 0.0625 vs thr 0.186); 1KB contiguous store/wave.

__device__ __forceinline__ h2 as_h2(unsigned v) {
    union { unsigned u; h2 h; } c; c.u = v; return c.h;
}

__device__ __forceinline__ float dot2x2(unsigned wlo, unsigned whi, h2 u01, h2 u23) {
#if __has_builtin(__builtin_amdgcn_fdot2)
    return __builtin_amdgcn_fdot2(as_h2(wlo), u01,
           __builtin_amdgcn_fdot2(as_h2(whi), u23, 0.0f, false), false);
#else
    h2 a = as_h2(wlo), b = as_h2(whi);
    return (float)a[0] * (float)u01[0] + (float)a[1] * (float)u01[1]
         + (float)b[0] * (float)u23[0] + (float)b[1] * (float)u23[1];
#endif
}

// ---------------- pre-pass: pack fp16 table into ws ----------------
__global__ __launch_bounds__(128) void k_build_wh(
    const float* __restrict__ W, char* __restrict__ Wh)
{
    const int s = blockIdx.x;     // 0..127
    const int j = threadIdx.x;    // 0..127
    float4 w = make_float4(0.0f, 0.0f, 0.0f, 0.0f);
    if (j != s) {
        const int k = j - (j > s);
        w = *reinterpret_cast<const float4*>(W + ((size_t)s * NM1 + k) * UDIM);
    }
    h2 a; a[0] = (_Float16)w.x; a[1] = (_Float16)w.y;
    h2 b; b[0] = (_Float16)w.z; b[1] = (_Float16)w.w;
    const size_t off = (size_t)s * 1024 + (size_t)((j >> 1) & 1) * 512
                     + (size_t)(j >> 2) * 16 + (size_t)(j & 1) * 8;
    *reinterpret_cast<h2*>(Wh + off)     = a;
    *reinterpret_cast<h2*>(Wh + off + 4) = b;
}

// ---------------- hot kernel ----------------
__global__ __launch_bounds__(1024) void k_seq(
    const int*   __restrict__ x_curr,
    const float* __restrict__ u_curr,
    const float* __restrict__ logP0,
    const uint4* __restrict__ Wh,
    float*       __restrict__ out,
    int T, int pairs_per_block)
{
    __shared__ uint4 wt[8192];    // 128 KB

    const int tid = threadIdx.x;
    #pragma unroll
    for (int i = 0; i < 8; ++i)
        wt[tid + i * 1024] = Wh[tid + i * 1024];
    __syncthreads();

    const int lane = tid & 63;
    const int wv   = tid >> 6;      // 0..15
    const int h    = lane >> 5;     // 0 = row 2p, 1 = row 2p+1
    const int lh   = lane & 31;
    const int j0   = 4 * lh;

    const int npairs = (T + 1) >> 1;
    const int pair0  = blockIdx.x * pairs_per_block;
    const int pairN  = (pair0 + pairs_per_block < npairs) ? (pair0 + pairs_per_block) : npairs;

    for (int p = pair0 + wv; p < pairN; p += 16) {
        const int r0 = 2 * p;
        const int r1 = (r0 + 1 < T) ? (r0 + 1) : r0;   // odd-T clamp (benign dup)

        int s0 = x_curr[r0], s1 = x_curr[r1];
        s0 = __builtin_amdgcn_readfirstlane(s0);
        s1 = __builtin_amdgcn_readfirstlane(s1);
        const int s = h ? s1 : s0;
        const int r = h ? r1 : r0;

        const float4 uv = *reinterpret_cast<const float4*>(u_curr + (size_t)r * UDIM);
        h2 u01; u01[0] = (_Float16)uv.x; u01[1] = (_Float16)uv.y;
        h2 u23; u23[0] = (_Float16)uv.z; u23[1] = (_Float16)uv.w;

        // cols 4lh,4lh+1 in w0; cols 4lh+2,4lh+3 in w1 (conflict-free b128)
        const uint4 w0 = wt[s * 64 + lh];
        const uint4 w1 = wt[s * 64 + 32 + lh];

        const float4 lp = *reinterpret_cast<const float4*>(logP0 + (size_t)s * NSTATE + j0);

        const float v0 = lp.x + dot2x2(w0.x, w0.y, u01, u23);
        const float v1 = lp.y + dot2x2(w0.z, w0.w, u01, u23);
        const float v2 = lp.z + dot2x2(w1.x, w1.y, u01, u23);
        const float v3 = lp.w + dot2x2(w1.z, w1.w, u01, u23);

        float e = (__expf(v0) + __expf(v1)) + (__expf(v2) + __expf(v3));
        #pragma unroll
        for (int o = 16; o >= 1; o >>= 1)
            e += __shfl_xor(e, o, 64);      // within 32-lane half
        const float l = __logf(e);

        v4f ov;
        ov[0] = v0 - l; ov[1] = v1 - l; ov[2] = v2 - l; ov[3] = v3 - l;
        *reinterpret_cast<v4f*>(out + (size_t)r * NSTATE + j0) = ov;   // PLAIN store
    }
}

// ---------------- fallback (ws too small): R8-style direct kernel ----------------
__device__ __forceinline__ float dot4(const float4 a, const float4 b) {
    return fmaf(a.x, b.x, fmaf(a.y, b.y, fmaf(a.z, b.z, a.w * b.w)));
}

__global__ __launch_bounds__(256) void k_fallback(
    const int* __restrict__ x_curr, const float* __restrict__ u_curr,
    const float* __restrict__ logP0, const float* __restrict__ W,
    float* __restrict__ out, int T)
{
    const int lane    = threadIdx.x & 63;
    const int wave_id = (blockIdx.x * blockDim.x + threadIdx.x) >> 6;
    const int nwaves  = (gridDim.x * blockDim.x) >> 6;
    const int j0 = 2 * lane, j1 = j0 + 1;
    for (int t = wave_id; t < T; t += nwaves) {
        int s = x_curr[t];
        s = __builtin_amdgcn_readfirstlane(s);
        const float4 uv = *reinterpret_cast<const float4*>(u_curr + (size_t)t * UDIM);
        float st0 = 0.0f, st1 = 0.0f;
        if (j0 != s) {
            const int k = j0 - (j0 > s);
            const float4 w = *reinterpret_cast<const float4*>(W + ((size_t)s * NM1 + k) * UDIM);
            st0 = dot4(uv, w);
        }
        if (j1 != s) {
            const int k = j1 - (j1 > s);
            const float4 w = *reinterpret_cast<const float4*>(W + ((size_t)s * NM1 + k) * UDIM);
            st1 = dot4(uv, w);
        }
        const float2 lp = *reinterpret_cast<const float2*>(logP0 + (size_t)s * NSTATE + j0);
        const float v0 = lp.x + st0, v1 = lp.y + st1;
        float e = __expf(v0) + __expf(v1);
        #pragma unroll
        for (int o = 32; o >= 1; o >>= 1)
            e += __shfl_xor(e, o, 64);
        const float l = __logf(e);
        float2 o2; o2.x = v0 - l; o2.y = v1 - l;
        *reinterpret_cast<float2*>(out + (size_t)t * NSTATE + j0) = o2;
    }
}

extern "C" void kernel_launch(void* const* d_in, const int* in_sizes, int n_in,
                              void* d_out, int out_size, void* d_ws, size_t ws_size,
                              hipStream_t stream) {
    const int*   x_curr = (const int*)  d_in[0];
    const float* u_curr = (const float*)d_in[1];
    const float* logP0  = (const float*)d_in[2];
    const float* W      = (const float*)d_in[3];
    float*       out    = (float*)d_out;

    const int T = in_sizes[0];
    const size_t need = 131072;   // 128 KB fp16 table

    if (ws_size < need || T < 2) {
        hipLaunchKernelGGL(k_fallback, dim3(2048), dim3(256), 0, stream,
                           x_curr, u_curr, logP0, W, out, T);
        return;
    }

    hipLaunchKernelGGL(k_build_wh, dim3(NSTATE), dim3(NSTATE), 0, stream,
                       W, (char*)d_ws);

    const int npairs = (T + 1) >> 1;
    const int nblk   = 256;                            // 1 block/CU (128KB LDS)
    const int ppb    = (npairs + nblk - 1) / nblk;     // contiguous pair span
    hipLaunchKernelGGL(k_seq, dim3(nblk), dim3(1024), 0, stream,
                       x_curr, u_curr, logP0, (const uint4*)d_ws, out, T, ppb);
}

// Round 16
// 66.432 us; speedup vs baseline: 1.4626x; 1.4626x over previous
//
#include <hip/hip_runtime.h>

#define NSTATE 128
#define NM1    127
#define UDIM   4

typedef float v4f  __attribute__((ext_vector_type(4)));
typedef _Float16 h2 __attribute__((ext_vector_type(2)));

// R16: R14 (best, 65.4us) with ONE change: the hot loop processes TWO pairs
// (p and p+16) per iteration, all loads for both issued before either
// compute -- 2x independent dependency chains per wave (8 per SIMD at 4
// waves/SIMD) to hide the x->RFL->{LDS w, lp}->dot->exp->5-shuffle->log
// chain (~600cy). Traffic, LDS layout, sweep order unchanged.
// NT STORES KEPT: R15 proved removing them costs +49% (65.4->97.2us) --
// 256MB streaming through 32MB L2 thrashes it and write-back scrambles
// store order; nt retires in (sequential) issue order.
// No-max softmax validated R2-R15 (absmax 0.0625 vs thr 0.186).

__device__ __forceinline__ h2 as_h2(unsigned v) {
    union { unsigned u; h2 h; } c; c.u = v; return c.h;
}

__device__ __forceinline__ float dot2x2(unsigned wlo, unsigned whi, h2 u01, h2 u23) {
#if __has_builtin(__builtin_amdgcn_fdot2)
    return __builtin_amdgcn_fdot2(as_h2(wlo), u01,
           __builtin_amdgcn_fdot2(as_h2(whi), u23, 0.0f, false), false);
#else
    h2 a = as_h2(wlo), b = as_h2(whi);
    return (float)a[0] * (float)u01[0] + (float)a[1] * (float)u01[1]
         + (float)b[0] * (float)u23[0] + (float)b[1] * (float)u23[1];
#endif
}

// ---------------- pre-pass: pack fp16 table into ws ----------------
__global__ __launch_bounds__(128) void k_build_wh(
    const float* __restrict__ W, char* __restrict__ Wh)
{
    const int s = blockIdx.x;     // 0..127
    const int j = threadIdx.x;    // 0..127
    float4 w = make_float4(0.0f, 0.0f, 0.0f, 0.0f);
    if (j != s) {
        const int k = j - (j > s);
        w = *reinterpret_cast<const float4*>(W + ((size_t)s * NM1 + k) * UDIM);
    }
    h2 a; a[0] = (_Float16)w.x; a[1] = (_Float16)w.y;
    h2 b; b[0] = (_Float16)w.z; b[1] = (_Float16)w.w;
    const size_t off = (size_t)s * 1024 + (size_t)((j >> 1) & 1) * 512
                     + (size_t)(j >> 2) * 16 + (size_t)(j & 1) * 8;
    *reinterpret_cast<h2*>(Wh + off)     = a;
    *reinterpret_cast<h2*>(Wh + off + 4) = b;
}

// ---------------- hot kernel ----------------
__global__ __launch_bounds__(1024) void k_seq(
    const int*   __restrict__ x_curr,
    const float* __restrict__ u_curr,
    const float* __restrict__ logP0,
    const uint4* __restrict__ Wh,
    float*       __restrict__ out,
    int T, int pairs_per_block)
{
    __shared__ uint4 wt[8192];    // 128 KB

    const int tid = threadIdx.x;
    #pragma unroll
    for (int i = 0; i < 8; ++i)
        wt[tid + i * 1024] = Wh[tid + i * 1024];
    __syncthreads();

    const int lane = tid & 63;
    const int wv   = tid >> 6;      // 0..15
    const int h    = lane >> 5;     // 0 = row 2p, 1 = row 2p+1
    const int lh   = lane & 31;
    const int j0   = 4 * lh;

    const int npairs = (T + 1) >> 1;
    const int pair0  = blockIdx.x * pairs_per_block;
    const int pairN  = (pair0 + pairs_per_block < npairs) ? (pair0 + pairs_per_block) : npairs;

    for (int p = pair0 + wv; p < pairN; p += 32) {
        const int  pB   = p + 16;
        const bool hasB = (pB < pairN);
        const int  pBc  = hasB ? pB : p;

        // ---- load phase: both pairs' x ----
        const int rA0 = 2 * p;
        const int rA1 = (rA0 + 1 < T) ? (rA0 + 1) : rA0;
        const int rB0 = 2 * pBc;
        const int rB1 = (rB0 + 1 < T) ? (rB0 + 1) : rB0;

        int xA0 = x_curr[rA0], xA1 = x_curr[rA1];
        int xB0 = x_curr[rB0], xB1 = x_curr[rB1];
        xA0 = __builtin_amdgcn_readfirstlane(xA0);
        xA1 = __builtin_amdgcn_readfirstlane(xA1);
        xB0 = __builtin_amdgcn_readfirstlane(xB0);
        xB1 = __builtin_amdgcn_readfirstlane(xB1);

        const int sA = h ? xA1 : xA0;
        const int rA = h ? rA1 : rA0;
        const int sB = h ? xB1 : xB0;
        const int rB = h ? rB1 : rB0;

        // ---- load phase: u, LDS w, lp for both pairs ----
        const float4 uvA = *reinterpret_cast<const float4*>(u_curr + (size_t)rA * UDIM);
        const float4 uvB = *reinterpret_cast<const float4*>(u_curr + (size_t)rB * UDIM);

        const uint4 wA0 = wt[sA * 64 + lh];
        const uint4 wA1 = wt[sA * 64 + 32 + lh];
        const uint4 wB0 = wt[sB * 64 + lh];
        const uint4 wB1 = wt[sB * 64 + 32 + lh];

        const float4 lpA = *reinterpret_cast<const float4*>(logP0 + (size_t)sA * NSTATE + j0);
        const float4 lpB = *reinterpret_cast<const float4*>(logP0 + (size_t)sB * NSTATE + j0);

        // ---- compute phase: two independent chains ----
        h2 uA01; uA01[0] = (_Float16)uvA.x; uA01[1] = (_Float16)uvA.y;
        h2 uA23; uA23[0] = (_Float16)uvA.z; uA23[1] = (_Float16)uvA.w;
        h2 uB01; uB01[0] = (_Float16)uvB.x; uB01[1] = (_Float16)uvB.y;
        h2 uB23; uB23[0] = (_Float16)uvB.z; uB23[1] = (_Float16)uvB.w;

        const float a0 = lpA.x + dot2x2(wA0.x, wA0.y, uA01, uA23);
        const float a1 = lpA.y + dot2x2(wA0.z, wA0.w, uA01, uA23);
        const float a2 = lpA.z + dot2x2(wA1.x, wA1.y, uA01, uA23);
        const float a3 = lpA.w + dot2x2(wA1.z, wA1.w, uA01, uA23);
        const float b0 = lpB.x + dot2x2(wB0.x, wB0.y, uB01, uB23);
        const float b1 = lpB.y + dot2x2(wB0.z, wB0.w, uB01, uB23);
        const float b2 = lpB.z + dot2x2(wB1.x, wB1.y, uB01, uB23);
        const float b3 = lpB.w + dot2x2(wB1.z, wB1.w, uB01, uB23);

        float eA = (__expf(a0) + __expf(a1)) + (__expf(a2) + __expf(a3));
        float eB = (__expf(b0) + __expf(b1)) + (__expf(b2) + __expf(b3));
        #pragma unroll
        for (int o = 16; o >= 1; o >>= 1) {
            eA += __shfl_xor(eA, o, 64);    // within 32-lane half
            eB += __shfl_xor(eB, o, 64);
        }
        const float lA = __logf(eA);
        const float lB = __logf(eB);

        // ---- store phase (nt) ----
        v4f oA;
        oA[0] = a0 - lA; oA[1] = a1 - lA; oA[2] = a2 - lA; oA[3] = a3 - lA;
        __builtin_nontemporal_store(
            oA, reinterpret_cast<v4f*>(out + (size_t)rA * NSTATE + j0));
        if (hasB) {
            v4f oB;
            oB[0] = b0 - lB; oB[1] = b1 - lB; oB[2] = b2 - lB; oB[3] = b3 - lB;
            __builtin_nontemporal_store(
                oB, reinterpret_cast<v4f*>(out + (size_t)rB * NSTATE + j0));
        }
    }
}

// ---------------- fallback (ws too small): R8-style direct kernel ----------------
__device__ __forceinline__ float dot4(const float4 a, const float4 b) {
    return fmaf(a.x, b.x, fmaf(a.y, b.y, fmaf(a.z, b.z, a.w * b.w)));
}

__global__ __launch_bounds__(256) void k_fallback(
    const int* __restrict__ x_curr, const float* __restrict__ u_curr,
    const float* __restrict__ logP0, const float* __restrict__ W,
    float* __restrict__ out, int T)
{
    const int lane    = threadIdx.x & 63;
    const int wave_id = (blockIdx.x * blockDim.x + threadIdx.x) >> 6;
    const int nwaves  = (gridDim.x * blockDim.x) >> 6;
    const int j0 = 2 * lane, j1 = j0 + 1;
    for (int t = wave_id; t < T; t += nwaves) {
        int s = x_curr[t];
        s = __builtin_amdgcn_readfirstlane(s);
        const float4 uv = *reinterpret_cast<const float4*>(u_curr + (size_t)t * UDIM);
        float st0 = 0.0f, st1 = 0.0f;
        if (j0 != s) {
            const int k = j0 - (j0 > s);
            const float4 w = *reinterpret_cast<const float4*>(W + ((size_t)s * NM1 + k) * UDIM);
            st0 = dot4(uv, w);
        }
        if (j1 != s) {
            const int k = j1 - (j1 > s);
            const float4 w = *reinterpret_cast<const float4*>(W + ((size_t)s * NM1 + k) * UDIM);
            st1 = dot4(uv, w);
        }
        const float2 lp = *reinterpret_cast<const float2*>(logP0 + (size_t)s * NSTATE + j0);
        const float v0 = lp.x + st0, v1 = lp.y + st1;
        float e = __expf(v0) + __expf(v1);
        #pragma unroll
        for (int o = 32; o >= 1; o >>= 1)
            e += __shfl_xor(e, o, 64);
        const float l = __logf(e);
        float2 o2; o2.x = v0 - l; o2.y = v1 - l;
        *reinterpret_cast<float2*>(out + (size_t)t * NSTATE + j0) = o2;
    }
}

extern "C" void kernel_launch(void* const* d_in, const int* in_sizes, int n_in,
                              void* d_out, int out_size, void* d_ws, size_t ws_size,
                              hipStream_t stream) {
    const int*   x_curr = (const int*)  d_in[0];
    const float* u_curr = (const float*)d_in[1];
    const float* logP0  = (const float*)d_in[2];
    const float* W      = (const float*)d_in[3];
    float*       out    = (float*)d_out;

    const int T = in_sizes[0];
    const size_t need = 131072;   // 128 KB fp16 table

    if (ws_size < need || T < 2) {
        hipLaunchKernelGGL(k_fallback, dim3(2048), dim3(256), 0, stream,
                           x_curr, u_curr, logP0, W, out, T);
        return;
    }

    hipLaunchKernelGGL(k_build_wh, dim3(NSTATE), dim3(NSTATE), 0, stream,
                       W, (char*)d_ws);

    const int npairs = (T + 1) >> 1;
    const int nblk   = 256;                            // 1 block/CU (128KB LDS)
    const int ppb    = (npairs + nblk - 1) / nblk;     // contiguous pair span
    hipLaunchKernelGGL(k_seq, dim3(nblk), dim3(1024), 0, stream,
                       x_curr, u_curr, logP0, (const uint4*)d_ws, out, T, ppb);
}

// Round 17
// 57.163 us; speedup vs baseline: 1.6998x; 1.1622x over previous
//
#include <hip/hip_runtime.h>

#define NSTATE 128
#define NM1    127
#define UDIM   4

typedef float v4f  __attribute__((ext_vector_type(4)));
typedef _Float16 h2 __attribute__((ext_vector_type(2)));

// R17: R14 (best, 65.4us) with ONE change: pair->wave mapping is grid-dense
// interleaved (p = blockIdx*16 + wv + iter*NWAVES) instead of per-block
// contiguous spans. At any instant the grid's nt stores form ONE dense ~4MB
// moving front (fillBuffer's pattern: consecutive blocks write consecutive
// granules concurrently), instead of 256 sequential streams spaced 1MB apart
// competing for DRAM pages. Reads are mapping-immune now: W table in LDS,
// x/u are dense-window streams, lp is 64KB L2-resident.
// NT stores kept (R15: removing them costs +49%). No-max softmax validated
// R2-R16 (absmax 0.0625 vs thr 0.186).

__device__ __forceinline__ h2 as_h2(unsigned v) {
    union { unsigned u; h2 h; } c; c.u = v; return c.h;
}

__device__ __forceinline__ float dot2x2(unsigned wlo, unsigned whi, h2 u01, h2 u23) {
#if __has_builtin(__builtin_amdgcn_fdot2)
    return __builtin_amdgcn_fdot2(as_h2(wlo), u01,
           __builtin_amdgcn_fdot2(as_h2(whi), u23, 0.0f, false), false);
#else
    h2 a = as_h2(wlo), b = as_h2(whi);
    return (float)a[0] * (float)u01[0] + (float)a[1] * (float)u01[1]
         + (float)b[0] * (float)u23[0] + (float)b[1] * (float)u23[1];
#endif
}

// ---------------- pre-pass: pack fp16 table into ws ----------------
__global__ __launch_bounds__(128) void k_build_wh(
    const float* __restrict__ W, char* __restrict__ Wh)
{
    const int s = blockIdx.x;     // 0..127
    const int j = threadIdx.x;    // 0..127
    float4 w = make_float4(0.0f, 0.0f, 0.0f, 0.0f);
    if (j != s) {
        const int k = j - (j > s);
        w = *reinterpret_cast<const float4*>(W + ((size_t)s * NM1 + k) * UDIM);
    }
    h2 a; a[0] = (_Float16)w.x; a[1] = (_Float16)w.y;
    h2 b; b[0] = (_Float16)w.z; b[1] = (_Float16)w.w;
    const size_t off = (size_t)s * 1024 + (size_t)((j >> 1) & 1) * 512
                     + (size_t)(j >> 2) * 16 + (size_t)(j & 1) * 8;
    *reinterpret_cast<h2*>(Wh + off)     = a;
    *reinterpret_cast<h2*>(Wh + off + 4) = b;
}

// ---------------- hot kernel ----------------
__global__ __launch_bounds__(1024) void k_seq(
    const int*   __restrict__ x_curr,
    const float* __restrict__ u_curr,
    const float* __restrict__ logP0,
    const uint4* __restrict__ Wh,
    float*       __restrict__ out,
    int T)
{
    __shared__ uint4 wt[8192];    // 128 KB

    const int tid = threadIdx.x;
    #pragma unroll
    for (int i = 0; i < 8; ++i)
        wt[tid + i * 1024] = Wh[tid + i * 1024];
    __syncthreads();

    const int lane = tid & 63;
    const int wv   = tid >> 6;      // 0..15
    const int h    = lane >> 5;     // 0 = row 2p, 1 = row 2p+1
    const int lh   = lane & 31;
    const int j0   = 4 * lh;

    const int npairs = (T + 1) >> 1;
    const int nw     = gridDim.x * 16;          // total waves (4096)
    const int pstart = blockIdx.x * 16 + wv;    // dense front: adjacent waves

    for (int p = pstart; p < npairs; p += nw) {
        const int r0 = 2 * p;
        const int r1 = (r0 + 1 < T) ? (r0 + 1) : r0;   // odd-T clamp (benign dup)

        int s0 = x_curr[r0], s1 = x_curr[r1];
        s0 = __builtin_amdgcn_readfirstlane(s0);
        s1 = __builtin_amdgcn_readfirstlane(s1);
        const int s = h ? s1 : s0;
        const int r = h ? r1 : r0;

        const float4 uv = *reinterpret_cast<const float4*>(u_curr + (size_t)r * UDIM);
        h2 u01; u01[0] = (_Float16)uv.x; u01[1] = (_Float16)uv.y;
        h2 u23; u23[0] = (_Float16)uv.z; u23[1] = (_Float16)uv.w;

        // cols 4lh,4lh+1 in w0; cols 4lh+2,4lh+3 in w1 (conflict-free b128)
        const uint4 w0 = wt[s * 64 + lh];
        const uint4 w1 = wt[s * 64 + 32 + lh];

        const float4 lp = *reinterpret_cast<const float4*>(logP0 + (size_t)s * NSTATE + j0);

        const float v0 = lp.x + dot2x2(w0.x, w0.y, u01, u23);
        const float v1 = lp.y + dot2x2(w0.z, w0.w, u01, u23);
        const float v2 = lp.z + dot2x2(w1.x, w1.y, u01, u23);
        const float v3 = lp.w + dot2x2(w1.z, w1.w, u01, u23);

        float e = (__expf(v0) + __expf(v1)) + (__expf(v2) + __expf(v3));
        #pragma unroll
        for (int o = 16; o >= 1; o >>= 1)
            e += __shfl_xor(e, o, 64);      // within 32-lane half
        const float l = __logf(e);

        v4f ov;
        ov[0] = v0 - l; ov[1] = v1 - l; ov[2] = v2 - l; ov[3] = v3 - l;
        __builtin_nontemporal_store(
            ov, reinterpret_cast<v4f*>(out + (size_t)r * NSTATE + j0));
    }
}

// ---------------- fallback (ws too small): R8-style direct kernel ----------------
__device__ __forceinline__ float dot4(const float4 a, const float4 b) {
    return fmaf(a.x, b.x, fmaf(a.y, b.y, fmaf(a.z, b.z, a.w * b.w)));
}

__global__ __launch_bounds__(256) void k_fallback(
    const int* __restrict__ x_curr, const float* __restrict__ u_curr,
    const float* __restrict__ logP0, const float* __restrict__ W,
    float* __restrict__ out, int T)
{
    const int lane    = threadIdx.x & 63;
    const int wave_id = (blockIdx.x * blockDim.x + threadIdx.x) >> 6;
    const int nwaves  = (gridDim.x * blockDim.x) >> 6;
    const int j0 = 2 * lane, j1 = j0 + 1;
    for (int t = wave_id; t < T; t += nwaves) {
        int s = x_curr[t];
        s = __builtin_amdgcn_readfirstlane(s);
        const float4 uv = *reinterpret_cast<const float4*>(u_curr + (size_t)t * UDIM);
        float st0 = 0.0f, st1 = 0.0f;
        if (j0 != s) {
            const int k = j0 - (j0 > s);
            const float4 w = *reinterpret_cast<const float4*>(W + ((size_t)s * NM1 + k) * UDIM);
            st0 = dot4(uv, w);
        }
        if (j1 != s) {
            const int k = j1 - (j1 > s);
            const float4 w = *reinterpret_cast<const float4*>(W + ((size_t)s * NM1 + k) * UDIM);
            st1 = dot4(uv, w);
        }
        const float2 lp = *reinterpret_cast<const float2*>(logP0 + (size_t)s * NSTATE + j0);
        const float v0 = lp.x + st0, v1 = lp.y + st1;
        float e = __expf(v0) + __expf(v1);
        #pragma unroll
        for (int o = 32; o >= 1; o >>= 1)
            e += __shfl_xor(e, o, 64);
        const float l = __logf(e);
        float2 o2; o2.x = v0 - l; o2.y = v1 - l;
        *reinterpret_cast<float2*>(out + (size_t)t * NSTATE + j0) = o2;
    }
}

extern "C" void kernel_launch(void* const* d_in, const int* in_sizes, int n_in,
                              void* d_out, int out_size, void* d_ws, size_t ws_size,
                              hipStream_t stream) {
    const int*   x_curr = (const int*)  d_in[0];
    const float* u_curr = (const float*)d_in[1];
    const float* logP0  = (const float*)d_in[2];
    const float* W      = (const float*)d_in[3];
    float*       out    = (float*)d_out;

    const int T = in_sizes[0];
    const size_t need = 131072;   // 128 KB fp16 table

    if (ws_size < need || T < 2) {
        hipLaunchKernelGGL(k_fallback, dim3(2048), dim3(256), 0, stream,
                           x_curr, u_curr, logP0, W, out, T);
        return;
    }

    hipLaunchKernelGGL(k_build_wh, dim3(NSTATE), dim3(NSTATE), 0, stream,
                       W, (char*)d_ws);

    // 256 blocks x 1024 thr (1 block/CU, 128KB LDS); grid-dense pair mapping.
    hipLaunchKernelGGL(k_seq, dim3(256), dim3(1024), 0, stream,
                       x_curr, u_curr, logP0, (const uint4*)d_ws, out, T);
}